// Round 16
// baseline (4560.558 us; speedup 1.0000x reference)
//
#include <hip/hip_runtime.h>

#define H 512
#define BATCHN 8192
#define STEPS 60
#define NWGS 256

// ws byte offsets
#define WEFF_OFF   0u
#define WPLAIN_OFF 2097152u
#define WIHS_OFF   4194304u
#define WSM_OFF    6291456u
#define BSM_OFF    6324224u
#define BX1_OFF    6324352u
#define BX0_OFF    6332544u
#define BAR_OFF    6340736u
#define XCDT_OFF   6340864u
#define FLAGS_OFF  6341888u
#define HB0_OFF    8388608u
#define HB1_OFF    16777216u
#define CPACK_OFF  25165824u
#define SPACK_OFF  41943040u

typedef short s16x8 __attribute__((ext_vector_type(8)));
typedef float f32x4 __attribute__((ext_vector_type(4)));
typedef unsigned int u32x2 __attribute__((ext_vector_type(2)));
typedef unsigned int u32x4 __attribute__((ext_vector_type(4)));

__device__ inline unsigned f2bf(float f) {
  unsigned u = __builtin_bit_cast(unsigned, f);
  return (u + 0x7fffu + ((u >> 16) & 1u)) >> 16;
}
__device__ inline float bf2f(unsigned s) {
  return __builtin_bit_cast(float, s << 16);
}
__device__ inline float sigm(float x) {
  float e = __builtin_amdgcn_exp2f(-1.442695041f * x);
  return __builtin_amdgcn_rcpf(1.0f + e);
}
__device__ inline float tanh_(float x) {
  float e = __builtin_amdgcn_exp2f(2.885390082f * x);
  return 1.0f - 2.0f * __builtin_amdgcn_rcpf(1.0f + e);
}
__device__ inline f32x4 mfma16(s16x8 a, s16x8 b, f32x4 c) {
  return __builtin_amdgcn_mfma_f32_16x16x32_bf16(a, b, c, 0, 0, 0);
}
__device__ inline int haddr(int b, int k) {
  return b * 1024 + ((k * 2) ^ ((b & 7) << 4));
}
__device__ inline void vm_drain() {
  asm volatile("s_waitcnt vmcnt(0)" ::: "memory");
  __builtin_amdgcn_sched_barrier(0);
}
// counted wait + scheduling fence (rule #18)
#define WAITV(n) do { \
  asm volatile("s_waitcnt vmcnt(" #n ")" ::: "memory"); \
  __builtin_amdgcn_sched_barrier(0); } while (0)

__device__ inline void stage_write(unsigned short* buf, int tid, const u32x4 sreg[4]) {
  int row = tid >> 4;
  char* b = (char*)buf + row * 1024;
  int off = (tid & 15) * 64;
  #pragma unroll
  for (int i = 0; i < 4; ++i)
    *(u32x4*)(b + ((off + i * 16) ^ ((row & 7) << 4))) = sreg[i];
}

// one-time global generation barrier (agent scope)
__device__ inline void global_barrier_once(unsigned* bar) {
  __syncthreads();
  if (threadIdx.x == 0) {
    unsigned a = __hip_atomic_fetch_add(bar, 1u, __ATOMIC_ACQ_REL, __HIP_MEMORY_SCOPE_AGENT);
    if (a == NWGS - 1) {
      __hip_atomic_store(bar + 16, 1u, __ATOMIC_RELEASE, __HIP_MEMORY_SCOPE_AGENT);
    } else {
      #pragma unroll 1
      while (__hip_atomic_load(bar + 16, __ATOMIC_ACQUIRE, __HIP_MEMORY_SCOPE_AGENT) == 0u)
        __builtin_amdgcn_s_sleep(2);
    }
  }
  __syncthreads();
}

// =================== pack kernel ===================
__global__ void pack_kernel(const float* __restrict__ w_ih, const float* __restrict__ w_hh,
                            const float* __restrict__ w_out, const float* __restrict__ b_out,
                            const float* __restrict__ w_mode, const float* __restrict__ b_mode,
                            unsigned char* __restrict__ ws) {
  unsigned idx = blockIdx.x * 256 + threadIdx.x;
  if (idx < 2097152u) {
    unsigned j = idx & 1048575u;
    bool eff = idx < 1048576u;
    unsigned e = j & 7u, lane = (j >> 3) & 63u, kb = (j >> 9) & 15u, T = j >> 13;
    unsigned i = lane & 15u;
    unsigned hcol = T * 4u + (i >> 2), gate = i & 3u;
    unsigned n = gate * 512u + hcol;
    unsigned k = kb * 32u + (lane >> 4) * 8u + e;
    float v = w_hh[(size_t)n * 512u + k];
    if (eff) v += w_ih[(size_t)n * 514u] * w_out[k] + w_ih[(size_t)n * 514u + 1u] * w_out[512u + k];
    ((unsigned short*)(ws + (eff ? WEFF_OFF : WPLAIN_OFF)))[j] = (unsigned short)f2bf(v);
  } else if (idx < 3145728u) {
    unsigned j = idx - 2097152u;
    unsigned e = j & 7u, lane = (j >> 3) & 63u, kb = (j >> 9) & 15u, nb = j >> 13;
    unsigned n = nb * 16u + (lane & 15u), k = kb * 32u + (lane >> 4) * 8u + e;
    ((unsigned short*)(ws + WIHS_OFF))[j] = (unsigned short)f2bf(w_ih[(size_t)n * 514u + 2u + k]);
  } else if (idx < 3162112u) {
    unsigned j = idx - 3145728u;
    unsigned e = j & 7u, lane = (j >> 3) & 63u, kb = (j >> 9) & 15u, nb = j >> 13;
    unsigned o = nb * 16u + (lane & 15u), k = kb * 32u + (lane >> 4) * 8u + e;
    float v = 0.0f;
    if (o < 12u) v = w_out[o * 512u + k];
    else if (o < 18u) v = w_mode[(o - 12u) * 512u + k];
    ((unsigned short*)(ws + WSM_OFF))[j] = (unsigned short)f2bf(v);
  } else if (idx < 3162144u) {
    unsigned o = idx - 3162112u;
    float v = 0.0f;
    if (o < 12u) v = b_out[o];
    else if (o < 18u) v = b_mode[o - 12u];
    ((float*)(ws + BSM_OFF))[o] = v;
  } else if (idx < 3164192u) {
    unsigned m = idx - 3162144u;
    unsigned T = m >> 4, i = m & 15u;
    unsigned hcol = T * 4u + (i >> 2), gate = i & 3u;
    unsigned n = gate * 512u + hcol;
    ((float*)(ws + BX1_OFF))[m] = w_ih[(size_t)n * 514u] * b_out[0] + w_ih[(size_t)n * 514u + 1u] * b_out[1];
  } else if (idx < 3166240u) {
    ((float*)(ws + BX0_OFF))[idx - 3164192u] = 0.0f;
  } else if (idx < 3166272u) {
    ((unsigned*)(ws + BAR_OFF))[idx - 3166240u] = 0u;
  } else if (idx < 3166528u) {
    ((unsigned*)(ws + XCDT_OFF))[idx - 3166272u] = 0xFFFFFFFFu;
  } else if (idx < 3168576u) {
    ((unsigned*)(ws + FLAGS_OFF))[idx - 3166528u] = 0u;
  }
}

// =================== prep kernel: S, h0->bf16, c0 repack ===================
__global__ __launch_bounds__(512, 2) void prep_kernel(
    const float* __restrict__ social, const float* __restrict__ hidden,
    const float* __restrict__ cell, const float* __restrict__ b_ih,
    const float* __restrict__ b_hh, unsigned char* __restrict__ ws) {
  const int tid = threadIdx.x;
  const int wid = tid >> 6;
  const int lane = tid & 63;
  const int q = lane >> 4;
  const int r = lane & 15;
  const int wg = blockIdx.x;
  const int gb0 = wg * 32;

  const s16x8* wihs_w = (const s16x8*)(ws + WIHS_OFF) + (size_t)wid * 4096 + lane;
  unsigned short* spack = (unsigned short*)(ws + SPACK_OFF);
  unsigned short* hb0 = (unsigned short*)(ws + HB0_OFF);
  float* cpackp = (float*)(ws + CPACK_OFF);

  __shared__ unsigned short h_lds[32 * H];

  s16x8 wbuf[4][4];
  #pragma unroll
  for (int d = 0; d < 4; ++d)
    #pragma unroll
    for (int g = 0; g < 4; ++g)
      wbuf[d][g] = wihs_w[g * 32768 + d * 64];

  #pragma unroll
  for (int i = 0; i < 8; ++i) {
    int rr = i * 4 + (tid >> 7);
    int kk = (tid & 127) * 4;
    f32x4 v = *(const f32x4*)(social + (size_t)(gb0 + rr) * H + kk);
    u32x2 p;
    p[0] = f2bf(v[0]) | (f2bf(v[1]) << 16);
    p[1] = f2bf(v[2]) | (f2bf(v[3]) << 16);
    *(u32x2*)((char*)h_lds + haddr(rr, kk)) = p;
  }
  __syncthreads();

  #pragma unroll
  for (int jb = 0; jb < 4; ++jb) {
    f32x4 acc[4][2];
    #pragma unroll
    for (int g = 0; g < 4; ++g) {
      int n0 = g * 512 + wid * 64 + jb * 16 + q * 4;
      f32x4 bi = *(const f32x4*)(b_ih + n0);
      f32x4 bh = *(const f32x4*)(b_hh + n0);
      f32x4 bias = bi + bh;
      acc[g][0] = bias; acc[g][1] = bias;
    }
    #pragma unroll
    for (int kb = 0; kb < 16; ++kb) {
      const int F = jb * 16 + kb;
      const int slot = F & 3;
      s16x8 bfrag[2];
      #pragma unroll
      for (int bb = 0; bb < 2; ++bb)
        bfrag[bb] = *(const s16x8*)((char*)h_lds + haddr(bb * 16 + r, kb * 32 + q * 8));
      s16x8 af[4];
      #pragma unroll
      for (int g = 0; g < 4; ++g) af[g] = wbuf[slot][g];
      {
        const int Fn = (F + 4) & 63;
        const int jn = Fn >> 4, kn = Fn & 15;
        #pragma unroll
        for (int g = 0; g < 4; ++g)
          wbuf[slot][g] = wihs_w[g * 32768 + jn * 1024 + kn * 64];
      }
      #pragma unroll
      for (int g = 0; g < 4; ++g) {
        acc[g][0] = mfma16(af[g], bfrag[0], acc[g][0]);
        acc[g][1] = mfma16(af[g], bfrag[1], acc[g][1]);
      }
    }
    #pragma unroll
    for (int bb = 0; bb < 2; ++bb) {
      unsigned wrd[8];
      #pragma unroll
      for (int j = 0; j < 8; ++j) {
        int e = j >> 1, gp = (j & 1) * 2;
        wrd[j] = f2bf(acc[gp][bb][e]) | (f2bf(acc[gp + 1][bb][e]) << 16);
      }
      int T = wid * 16 + jb * 4 + q;
      int b = gb0 + bb * 16 + r;
      char* dst = (char*)spack + ((size_t)T * 8192 + b) * 32;
      u32x4 w0; w0[0] = wrd[0]; w0[1] = wrd[1]; w0[2] = wrd[2]; w0[3] = wrd[3];
      u32x4 w1; w1[0] = wrd[4]; w1[1] = wrd[5]; w1[2] = wrd[6]; w1[3] = wrd[7];
      *(u32x4*)dst = w0;
      *(u32x4*)(dst + 16) = w1;
    }
  }

  {
    const float* hsrc = hidden + (size_t)gb0 * H;
    unsigned short* hdst = hb0 + (size_t)gb0 * H;
    int base = tid * 32;
    #pragma unroll
    for (int v8 = 0; v8 < 4; ++v8) {
      f32x4 x0 = *(const f32x4*)(hsrc + base + v8 * 8);
      f32x4 x1 = *(const f32x4*)(hsrc + base + v8 * 8 + 4);
      u32x4 pk;
      pk[0] = f2bf(x0[0]) | (f2bf(x0[1]) << 16);
      pk[1] = f2bf(x0[2]) | (f2bf(x0[3]) << 16);
      pk[2] = f2bf(x1[0]) | (f2bf(x1[1]) << 16);
      pk[3] = f2bf(x1[2]) | (f2bf(x1[3]) << 16);
      *(u32x4*)(hdst + base + v8 * 8) = pk;
    }
  }

  for (int j = 0; j < 32; ++j) {
    int flat = tid * 32 + j;
    int b = gb0 + (flat >> 9);
    int hcol = flat & 511;
    float v = cell[(size_t)b * 512 + hcol];
    int jg2 = hcol >> 6, w2 = (hcol >> 3) & 7, Tl = (hcol >> 2) & 1, q2 = hcol & 3;
    int bg2 = b >> 8, ib2 = (b >> 4) & 15, r2 = b & 15;
    int wg2 = jg2 * 32 + bg2;
    cpackp[(((size_t)(wg2 * 8 + w2) * 16 + ib2) * 2 + Tl) * 64 + q2 * 16 + r2] = v;
  }
}

// =================== persistent kernel: all 60 steps ===================
// Invariant: retire -> snapshot -> reissue (single sv/sreg buffers).
//   Prologue: H0,SC0 -> WAITV(0) -> write hin0 -> issue H1
//   Phase rr: top (rr>0: WAITV(4); rr==7: WAITV(0)) [SC(rr) retired]
//             snapshot ps<-sv; rr<7: ISSUE_SC(rr+1)
//             compute on ps
//             rr<7: WAITV(8) [H(rr+1) retired]; stage_write; rr<=5: ISSUE_H(rr+2)
//             sync
// Wait counts verified under both vmcnt store-retirement models.
__global__ __attribute__((amdgpu_flat_work_group_size(512, 512), amdgpu_waves_per_eu(2, 2)))
void coop_kernel(
    const s16x8* __restrict__ weff, const s16x8* __restrict__ wplain,
    const float* __restrict__ bx, const unsigned short* __restrict__ spack,
    const s16x8* __restrict__ wsm, const float* __restrict__ bsm,
    unsigned short* __restrict__ hb0, unsigned short* __restrict__ hb1,
    float* __restrict__ cpack, float* __restrict__ out,
    unsigned* __restrict__ flags, unsigned* __restrict__ xcdt,
    unsigned* __restrict__ bar) {
  const int tid = threadIdx.x;
  const int wid = tid >> 6;
  const int lane = tid & 63;
  const int q = lane >> 4;
  const int r = lane & 15;
  const int wg = blockIdx.x;
  const int jg = wg >> 5;
  const int bg = wg & 31;
  const int b0 = bg * 256;
  const size_t MODE_BASE = (size_t)BATCHN * 720;

  __shared__ s16x8 wsm_lds[2048];                 // 32 KB
  __shared__ unsigned short hinA[32 * 512];       // 32 KB
  __shared__ unsigned short hinB[32 * 512];       // 32 KB
  __shared__ unsigned short hout_lds[256 * 64];   // 32 KB
  __shared__ float mode_lds[8][16][8];            // 4 KB
  __shared__ float bx_lds[256];
  __shared__ float bsm_lds[32];
  __shared__ int fastf_lds;

  unsigned xcd;
  asm volatile("s_getreg_b32 %0, hwreg(20, 0, 32)" : "=s"(xcd));
  if (tid == 0)
    __hip_atomic_store(&xcdt[wg], xcd & 0xFu, __ATOMIC_RELEASE, __HIP_MEMORY_SCOPE_AGENT);

  // A fragments pinned via direct asm loads
  s16x8 A0[16], A1[16];
  {
    const s16x8* ab = wplain + (size_t)((jg * 16 + wid * 2) * 16) * 64 + lane;
    #pragma unroll
    for (int kb = 0; kb < 16; ++kb) {
      asm volatile("global_load_dwordx4 %0, %1, off" : "=v"(A0[kb]) : "v"(ab + kb * 64));
      asm volatile("global_load_dwordx4 %0, %1, off" : "=v"(A1[kb]) : "v"(ab + kb * 64 + 1024));
    }
  }
  vm_drain();

  float* cb = cpack + (size_t)(wg * 8 + wid) * 2048 + lane;
  const char* sp0b = (const char*)spack + ((size_t)(jg * 16 + wid * 2 + 0) * 8192 + (b0 + r)) * 32 + q * 8;
  const char* sp1b = (const char*)spack + ((size_t)(jg * 16 + wid * 2 + 1) * 8192 + (b0 + r)) * 32 + q * 8;

  #pragma unroll
  for (int i = 0; i < 4; ++i) wsm_lds[i * 512 + tid] = wsm[i * 512 + tid];
  if (tid < 256) bx_lds[tid] = bx[jg * 256 + tid];
  if (tid < 32) bsm_lds[tid] = bsm[tid];

  global_barrier_once(bar);
  if (tid == 0) {
    unsigned mine = xcd & 0xFu;
    bool same = true;
    for (int j = 0; j < 8; ++j) {
      unsigned v = __hip_atomic_load(&xcdt[bg + 32 * j], __ATOMIC_ACQUIRE, __HIP_MEMORY_SCOPE_AGENT);
      same = same && (v == mine);
    }
    fastf_lds = same ? 1 : 0;
  }
  __syncthreads();
  const bool fast = (fastf_lds != 0);

  u32x4 sreg[4];
  u32x2 sv_e0, sv_e1, sv_o0, sv_o1;
  float cv_e0, cv_e1, cv_o0, cv_o1;

#define ISSUE_H(p) do { \
    const char* pb_ = (const char*)h_in + (size_t)(b0 + (p) * 32 + (tid >> 4)) * 1024 + (tid & 15) * 64; \
    if (fast) { \
      asm volatile("global_load_dwordx4 %0, %1, off sc0" : "=v"(sreg[0]) : "v"(pb_)); \
      asm volatile("global_load_dwordx4 %0, %1, off offset:16 sc0" : "=v"(sreg[1]) : "v"(pb_)); \
      asm volatile("global_load_dwordx4 %0, %1, off offset:32 sc0" : "=v"(sreg[2]) : "v"(pb_)); \
      asm volatile("global_load_dwordx4 %0, %1, off offset:48 sc0" : "=v"(sreg[3]) : "v"(pb_)); \
    } else { \
      asm volatile("global_load_dwordx4 %0, %1, off sc0 sc1" : "=v"(sreg[0]) : "v"(pb_)); \
      asm volatile("global_load_dwordx4 %0, %1, off offset:16 sc0 sc1" : "=v"(sreg[1]) : "v"(pb_)); \
      asm volatile("global_load_dwordx4 %0, %1, off offset:32 sc0 sc1" : "=v"(sreg[2]) : "v"(pb_)); \
      asm volatile("global_load_dwordx4 %0, %1, off offset:48 sc0 sc1" : "=v"(sreg[3]) : "v"(pb_)); \
    } } while (0)

#define ISSUE_SC(p) do { \
    asm volatile("global_load_dwordx2 %0, %1, off" : "=v"(sv_e0) : "v"(sp0b + (p) * 1024)); \
    asm volatile("global_load_dwordx2 %0, %1, off" : "=v"(sv_e1) : "v"(sp1b + (p) * 1024)); \
    asm volatile("global_load_dwordx2 %0, %1, off" : "=v"(sv_o0) : "v"(sp0b + (p) * 1024 + 512)); \
    asm volatile("global_load_dwordx2 %0, %1, off" : "=v"(sv_o1) : "v"(sp1b + (p) * 1024 + 512)); \
    asm volatile("global_load_dword %0, %1, off" : "=v"(cv_e0) : "v"(cb + (p) * 256)); \
    asm volatile("global_load_dword %0, %1, off" : "=v"(cv_e1) : "v"(cb + (p) * 256 + 64)); \
    asm volatile("global_load_dword %0, %1, off" : "=v"(cv_o0) : "v"(cb + (p) * 256 + 128)); \
    asm volatile("global_load_dword %0, %1, off" : "=v"(cv_o1) : "v"(cb + (p) * 256 + 192)); \
  } while (0)

  #pragma unroll 1
  for (int s = 0; s < STEPS; ++s) {
    const unsigned short* h_in = (s & 1) ? hb1 : hb0;
    unsigned short* h_out = (s & 1) ? hb0 : hb1;
    f32x4 bz0 = *(const f32x4*)&bx_lds[wid * 32 + q * 4];
    f32x4 bz1 = *(const f32x4*)&bx_lds[wid * 32 + 16 + q * 4];
    if (s == 0) {
      f32x4 z = {0.f, 0.f, 0.f, 0.f};
      bz0 = z; bz1 = z;
    }

    // prologue: H0,SC0 -> drain -> write hin0 -> issue H1 (NOT SC1)
    ISSUE_H(0);
    ISSUE_SC(0);
    WAITV(0);
    stage_write(hinA, tid, sreg);
    ISSUE_H(1);
    __syncthreads();

    #pragma unroll
    for (int rr = 0; rr < 8; ++rr) {
      const int k = rr & 1;
      // top: ensure SC(rr) retired (rr0: retired in prologue)
      if (rr == 7)      WAITV(0);
      else if (rr > 0)  WAITV(4);

      // snapshot BEFORE reissue — sv holds retired SC(rr)
      u32x2 ps_e0 = sv_e0, ps_e1 = sv_e1, ps_o0 = sv_o0, ps_o1 = sv_o1;
      float pc_e0 = cv_e0, pc_e1 = cv_e1, pc_o0 = cv_o0, pc_o1 = cv_o1;
      if (rr < 7) ISSUE_SC(rr + 1);

      const unsigned short* hbuf = k ? hinB : hinA;
      const bool dop = (wid == rr) && (s > 0);
      #pragma unroll
      for (int ib2 = 0; ib2 < 2; ++ib2) {
        const int bt = rr * 2 + ib2;
        const int b = b0 + bt * 16 + r;
        u32x2 cs0 = ib2 ? ps_o0 : ps_e0;
        u32x2 cs1 = ib2 ? ps_o1 : ps_e1;
        float cva0 = ib2 ? pc_o0 : pc_e0;
        float cva1 = ib2 ? pc_o1 : pc_e1;
        f32x4 acc0, acc1;
        acc0[0] = bf2f(cs0[0] & 0xffffu) + bz0[0];
        acc0[1] = bf2f(cs0[0] >> 16)     + bz0[1];
        acc0[2] = bf2f(cs0[1] & 0xffffu) + bz0[2];
        acc0[3] = bf2f(cs0[1] >> 16)     + bz0[3];
        acc1[0] = bf2f(cs1[0] & 0xffffu) + bz1[0];
        acc1[1] = bf2f(cs1[0] >> 16)     + bz1[1];
        acc1[2] = bf2f(cs1[1] & 0xffffu) + bz1[2];
        acc1[3] = bf2f(cs1[1] >> 16)     + bz1[3];
        #pragma unroll
        for (int kb = 0; kb < 16; ++kb) {
          s16x8 bfrag = *(const s16x8*)((const char*)hbuf + (ib2 * 16 + r) * 1024 +
                          ((kb * 64 + q * 16) ^ ((r & 7) << 4)));
          acc0 = mfma16(A0[kb], bfrag, acc0);
          acc1 = mfma16(A1[kb], bfrag, acc1);
        }
        #pragma unroll
        for (int Tl = 0; Tl < 2; ++Tl) {
          f32x4 ac = Tl ? acc1 : acc0;
          float cold = Tl ? cva1 : cva0;
          float iv = sigm(ac[0]), fv = sigm(ac[1]), gv = tanh_(ac[2]), ov = sigm(ac[3]);
          float cn = fv * cold + iv * gv;
          asm volatile("global_store_dword %0, %1, off"
                       :: "v"(cb + bt * 128 + Tl * 64), "v"(cn));
          float hn = ov * tanh_(cn);
          int col = wid * 8 + Tl * 4 + q;
          int row = bt * 16 + r;
          *(unsigned short*)((char*)hout_lds + row * 128 + ((col * 2) ^ ((r & 7) << 4))) =
              (unsigned short)f2bf(hn);
        }
        if (dop) {
          const int tprev = s - 1;
          f32x4 p0 = *(const f32x4*)&bsm_lds[q * 4];
          f32x4 p1 = *(const f32x4*)&bsm_lds[16 + q * 4];
          #pragma unroll
          for (int kb = 0; kb < 16; ++kb) {
            s16x8 bfrag = *(const s16x8*)((const char*)hbuf + (ib2 * 16 + r) * 1024 +
                            ((kb * 64 + q * 16) ^ ((r & 7) << 4)));
            p0 = mfma16(wsm_lds[kb * 64 + lane], bfrag, p0);
            p1 = mfma16(wsm_lds[(16 + kb) * 64 + lane], bfrag, p1);
          }
          if (q < 3)
            asm volatile("global_store_dwordx4 %0, %1, off"
                         :: "v"(out + ((size_t)b * 60 + tprev) * 12 + q * 4), "v"(p0));
          if (q == 3) *(f32x4*)(&mode_lds[wid][r][0]) = p0;
          if (q == 0) { mode_lds[wid][r][4] = p1[0]; mode_lds[wid][r][5] = p1[1]; }
          if (q == 1) {
            float v0 = mode_lds[wid][r][0], v1 = mode_lds[wid][r][1], v2 = mode_lds[wid][r][2];
            float v3 = mode_lds[wid][r][3], v4 = mode_lds[wid][r][4], v5 = mode_lds[wid][r][5];
            float mx = fmaxf(fmaxf(fmaxf(v0, v1), fmaxf(v2, v3)), fmaxf(v4, v5));
            float e0 = __builtin_amdgcn_exp2f(1.442695041f * (v0 - mx));
            float e1 = __builtin_amdgcn_exp2f(1.442695041f * (v1 - mx));
            float e2 = __builtin_amdgcn_exp2f(1.442695041f * (v2 - mx));
            float e3 = __builtin_amdgcn_exp2f(1.442695041f * (v3 - mx));
            float e4 = __builtin_amdgcn_exp2f(1.442695041f * (v4 - mx));
            float e5 = __builtin_amdgcn_exp2f(1.442695041f * (v5 - mx));
            float su = e0 + e1 + e2 + e3 + e4 + e5;
            float inv = __builtin_amdgcn_rcpf(su);
            float* mo = out + MODE_BASE + (size_t)b * 360 + tprev * 6;
            u32x2 m01, m23, m45;
            m01[0] = __builtin_bit_cast(unsigned, e0 * inv);
            m01[1] = __builtin_bit_cast(unsigned, e1 * inv);
            m23[0] = __builtin_bit_cast(unsigned, e2 * inv);
            m23[1] = __builtin_bit_cast(unsigned, e3 * inv);
            m45[0] = __builtin_bit_cast(unsigned, e4 * inv);
            m45[1] = __builtin_bit_cast(unsigned, e5 * inv);
            asm volatile("global_store_dwordx2 %0, %1, off" :: "v"(mo), "v"(m01));
            asm volatile("global_store_dwordx2 %0, %1, off" :: "v"(mo + 2), "v"(m23));
            asm volatile("global_store_dwordx2 %0, %1, off" :: "v"(mo + 4), "v"(m45));
          }
        }
      }
      // post: H(rr+1) retired -> stage it; issue H(rr+2)
      if (rr < 7) {
        WAITV(8);
        stage_write(((rr + 1) & 1) ? hinB : hinA, tid, sreg);
        if (rr <= 5) ISSUE_H(rr + 2);
      }
      __syncthreads();
    }

    // flush h_out (hout_lds complete after rr7's sync)
    {
      int row = tid >> 1;
      int off0 = (tid & 1) * 64;
      u32x4 v0 = *(const u32x4*)((const char*)hout_lds + row * 128 + ((off0 +  0) ^ ((row & 7) << 4)));
      u32x4 v1 = *(const u32x4*)((const char*)hout_lds + row * 128 + ((off0 + 16) ^ ((row & 7) << 4)));
      u32x4 v2 = *(const u32x4*)((const char*)hout_lds + row * 128 + ((off0 + 32) ^ ((row & 7) << 4)));
      u32x4 v3 = *(const u32x4*)((const char*)hout_lds + row * 128 + ((off0 + 48) ^ ((row & 7) << 4)));
      char* dst = (char*)h_out + (size_t)(b0 + row) * 1024 + jg * 128 + off0;
      if (fast) {
        asm volatile(
            "global_store_dwordx4 %0, %1, off\n\t"
            "global_store_dwordx4 %0, %2, off offset:16\n\t"
            "global_store_dwordx4 %0, %3, off offset:32\n\t"
            "global_store_dwordx4 %0, %4, off offset:48"
            :: "v"(dst), "v"(v0), "v"(v1), "v"(v2), "v"(v3) : "memory");
      } else {
        asm volatile(
            "global_store_dwordx4 %0, %1, off sc0 sc1\n\t"
            "global_store_dwordx4 %0, %2, off offset:16 sc0 sc1\n\t"
            "global_store_dwordx4 %0, %3, off offset:32 sc0 sc1\n\t"
            "global_store_dwordx4 %0, %4, off offset:48 sc0 sc1"
            :: "v"(dst), "v"(v0), "v"(v1), "v"(v2), "v"(v3) : "memory");
      }
      asm volatile("s_waitcnt vmcnt(0)" ::: "memory");
    }
    if (s < STEPS - 1) {
      __syncthreads();
      if (tid == 0) {
        unsigned* f = &flags[bg * 64 + s];
        __hip_atomic_fetch_add(f, 1u, __ATOMIC_RELAXED, __HIP_MEMORY_SCOPE_AGENT);
        unsigned v;
        #pragma unroll 1
        do {
          v = __hip_atomic_load(f, __ATOMIC_RELAXED, __HIP_MEMORY_SCOPE_AGENT);
          if (v < 8u) __builtin_amdgcn_s_sleep(1);
        } while (v < 8u);
      }
      __syncthreads();
    }
    if (s == 0) {
      const s16x8* ab = weff + (size_t)((jg * 16 + wid * 2) * 16) * 64 + lane;
      #pragma unroll
      for (int kb = 0; kb < 16; ++kb) {
        asm volatile("global_load_dwordx4 %0, %1, off" : "=v"(A0[kb]) : "v"(ab + kb * 64));
        asm volatile("global_load_dwordx4 %0, %1, off" : "=v"(A1[kb]) : "v"(ab + kb * 64 + 1024));
      }
      vm_drain();
    }
  }
#undef ISSUE_H
#undef ISSUE_SC
}

// =================== final projection (t=59), sc1 h loads ===================
__global__ __launch_bounds__(256) void projf_kernel(
    const unsigned short* __restrict__ h_in, const s16x8* __restrict__ wsm,
    const float* __restrict__ bsm, float* __restrict__ out) {
  const int tid = threadIdx.x;
  const int wid = tid >> 6;
  const int lane = tid & 63;
  const int q = lane >> 4;
  const int r = lane & 15;
  const int wg = blockIdx.x;
  const int b0 = wg * 32;
  const int bt = wid & 1, T = wid >> 1;
  const size_t MODE_BASE = (size_t)BATCHN * 720;
  __shared__ float mbuf[32][8];

  u32x4 hf[16];
  const char* hbase = (const char*)h_in + (size_t)(b0 + bt * 16 + r) * 1024 + q * 16;
  #pragma unroll
  for (int g = 0; g < 16; ++g) {
    asm volatile("global_load_dwordx4 %0, %1, off sc0 sc1"
                 : "=v"(hf[g]) : "v"(hbase + g * 64));
  }
  asm volatile("s_waitcnt vmcnt(0)" ::: "memory");
  __builtin_amdgcn_sched_barrier(0);

  f32x4 pacc = *(const f32x4*)(bsm + T * 16 + q * 4);
  #pragma unroll
  for (int kb = 0; kb < 16; ++kb) {
    s16x8 bfrag = __builtin_bit_cast(s16x8, hf[kb]);
    s16x8 af = wsm[(T * 16 + kb) * 64 + lane];
    pacc = mfma16(af, bfrag, pacc);
  }
  int b = b0 + bt * 16 + r;
  if (T == 0) {
    if (q < 3) *(f32x4*)(out + ((size_t)b * 60 + 59) * 12 + q * 4) = pacc;
    if (q == 3) *(f32x4*)(&mbuf[bt * 16 + r][0]) = pacc;
  } else {
    if (q == 0) { mbuf[bt * 16 + r][4] = pacc[0]; mbuf[bt * 16 + r][5] = pacc[1]; }
  }
  __syncthreads();
  if (tid < 32) {
    float v0 = mbuf[tid][0], v1 = mbuf[tid][1], v2 = mbuf[tid][2];
    float v3 = mbuf[tid][3], v4 = mbuf[tid][4], v5 = mbuf[tid][5];
    float mx = fmaxf(fmaxf(fmaxf(v0, v1), fmaxf(v2, v3)), fmaxf(v4, v5));
    float e0 = __builtin_amdgcn_exp2f(1.442695041f * (v0 - mx));
    float e1 = __builtin_amdgcn_exp2f(1.442695041f * (v1 - mx));
    float e2 = __builtin_amdgcn_exp2f(1.442695041f * (v2 - mx));
    float e3 = __builtin_amdgcn_exp2f(1.442695041f * (v3 - mx));
    float e4 = __builtin_amdgcn_exp2f(1.442695041f * (v4 - mx));
    float e5 = __builtin_amdgcn_exp2f(1.442695041f * (v5 - mx));
    float s = e0 + e1 + e2 + e3 + e4 + e5;
    float inv = __builtin_amdgcn_rcpf(s);
    float* mo = out + MODE_BASE + (size_t)(b0 + tid) * 360 + 59 * 6;
    mo[0] = e0 * inv; mo[1] = e1 * inv; mo[2] = e2 * inv;
    mo[3] = e3 * inv; mo[4] = e4 * inv; mo[5] = e5 * inv;
  }
}

extern "C" void kernel_launch(void* const* d_in, const int* in_sizes, int n_in,
                              void* d_out, int out_size, void* d_ws, size_t ws_size,
                              hipStream_t stream) {
  const float* social = (const float*)d_in[0];
  const float* hidden = (const float*)d_in[1];
  const float* cell   = (const float*)d_in[2];
  const float* w_ih   = (const float*)d_in[3];
  const float* w_hh   = (const float*)d_in[4];
  const float* b_ih   = (const float*)d_in[5];
  const float* b_hh   = (const float*)d_in[6];
  const float* w_out  = (const float*)d_in[7];
  const float* b_out  = (const float*)d_in[8];
  const float* w_mode = (const float*)d_in[9];
  const float* b_mode = (const float*)d_in[10];
  unsigned char* ws = (unsigned char*)d_ws;
  float* out = (float*)d_out;

  hipLaunchKernelGGL(pack_kernel, dim3((3168576u + 255u) / 256u), dim3(256), 0, stream,
                     w_ih, w_hh, w_out, b_out, w_mode, b_mode, ws);
  hipLaunchKernelGGL(prep_kernel, dim3(256), dim3(512), 0, stream,
                     social, hidden, cell, b_ih, b_hh, ws);

  const s16x8* weff   = (const s16x8*)(ws + WEFF_OFF);
  const s16x8* wplain = (const s16x8*)(ws + WPLAIN_OFF);
  const s16x8* wsm    = (const s16x8*)(ws + WSM_OFF);
  const float* bsm    = (const float*)(ws + BSM_OFF);
  const float* bx1    = (const float*)(ws + BX1_OFF);
  const unsigned short* spack = (const unsigned short*)(ws + SPACK_OFF);
  unsigned short* hb0p = (unsigned short*)(ws + HB0_OFF);
  unsigned short* hb1p = (unsigned short*)(ws + HB1_OFF);
  float* cpackc = (float*)(ws + CPACK_OFF);
  unsigned* flagsp = (unsigned*)(ws + FLAGS_OFF);
  unsigned* xcdtp = (unsigned*)(ws + XCDT_OFF);
  unsigned* barp = (unsigned*)(ws + BAR_OFF);

  void* args[] = {(void*)&weff, (void*)&wplain, (void*)&bx1, (void*)&spack,
                  (void*)&wsm, (void*)&bsm, (void*)&hb0p, (void*)&hb1p,
                  (void*)&cpackc, (void*)&out, (void*)&flagsp, (void*)&xcdtp,
                  (void*)&barp};
  hipLaunchCooperativeKernel((const void*)coop_kernel, dim3(NWGS), dim3(512),
                             args, 0, stream);

  hipLaunchKernelGGL(projf_kernel, dim3(256), dim3(256), 0, stream,
                     hb0p, wsm, bsm, out);
}

// Round 17
// 4092.274 us; speedup vs baseline: 1.1144x; 1.1144x over previous
//
#include <hip/hip_runtime.h>

#define H 512
#define BATCHN 8192
#define STEPS 60
#define NWGS 256

// ws byte offsets
#define WEFF_OFF   0u          // 2 MB  w_hh_eff pack (tile layout)
#define WPLAIN_OFF 2097152u    // 2 MB  w_hh pack (t=0)
#define WIHS_OFF   4194304u    // 2 MB  w_ih social cols pack (prep, old layout)
#define WSM_OFF    6291456u    // 32 KB [w_out;w_mode] pack
#define BSM_OFF    6324224u    // 128 B proj bias
#define BX1_OFF    6324352u    // 8 KB  bias_x (tile-row order)
#define BX0_OFF    6332544u    // 8 KB  zeros (unused)
#define BAR_OFF    6340736u    // 128 B one-time global barrier {count,...,gen}
#define XCDT_OFF   6340864u    // 1 KB  per-WG xcd id
#define FLAGS_OFF  6341888u    // 8 KB  flags[bg*64+s] arrival counters (init 0)
#define HB0_OFF    8388608u    // 8 MB  h buffer 0 (bf16)
#define HB1_OFF    16777216u   // 8 MB  h buffer 1
#define CPACK_OFF  25165824u   // 16 MB c packed f32
#define SPACK_OFF  41943040u   // 32 MB S packed bf16

typedef short s16x8 __attribute__((ext_vector_type(8)));
typedef float f32x4 __attribute__((ext_vector_type(4)));
typedef unsigned int u32x2 __attribute__((ext_vector_type(2)));
typedef unsigned int u32x4 __attribute__((ext_vector_type(4)));

__device__ inline unsigned f2bf(float f) {
  unsigned u = __builtin_bit_cast(unsigned, f);
  return (u + 0x7fffu + ((u >> 16) & 1u)) >> 16;
}
__device__ inline float bf2f(unsigned s) {
  return __builtin_bit_cast(float, s << 16);
}
__device__ inline float sigm(float x) {
  float e = __builtin_amdgcn_exp2f(-1.442695041f * x);
  return __builtin_amdgcn_rcpf(1.0f + e);
}
__device__ inline float tanh_(float x) {
  float e = __builtin_amdgcn_exp2f(2.885390082f * x);
  return 1.0f - 2.0f * __builtin_amdgcn_rcpf(1.0f + e);
}
__device__ inline f32x4 mfma16(s16x8 a, s16x8 b, f32x4 c) {
  return __builtin_amdgcn_mfma_f32_16x16x32_bf16(a, b, c, 0, 0, 0);
}
__device__ inline int haddr(int b, int k) {
  return b * 1024 + ((k * 2) ^ ((b & 7) << 4));
}

__device__ inline void vm_drain() {
  asm volatile("s_waitcnt vmcnt(0)" ::: "memory");
  __builtin_amdgcn_sched_barrier(0);
}

// -------- h exchange: fast = same-XCD via L2 (plain store / sc0 load),
//          slow = device-scope sc1 (correct on any placement) --------
__device__ inline void stage_issue(const unsigned short* h_in, int b0, int p, int tid,
                                   bool fast, u32x4 sreg[4]) {
  const char* pb = (const char*)h_in + (size_t)(b0 + p * 32 + (tid >> 4)) * 1024 +
                   (tid & 15) * 64;
  if (fast) {
    asm volatile("global_load_dwordx4 %0, %1, off sc0" : "=v"(sreg[0]) : "v"(pb));
    asm volatile("global_load_dwordx4 %0, %1, off offset:16 sc0" : "=v"(sreg[1]) : "v"(pb));
    asm volatile("global_load_dwordx4 %0, %1, off offset:32 sc0" : "=v"(sreg[2]) : "v"(pb));
    asm volatile("global_load_dwordx4 %0, %1, off offset:48 sc0" : "=v"(sreg[3]) : "v"(pb));
  } else {
    asm volatile("global_load_dwordx4 %0, %1, off sc0 sc1" : "=v"(sreg[0]) : "v"(pb));
    asm volatile("global_load_dwordx4 %0, %1, off offset:16 sc0 sc1" : "=v"(sreg[1]) : "v"(pb));
    asm volatile("global_load_dwordx4 %0, %1, off offset:32 sc0 sc1" : "=v"(sreg[2]) : "v"(pb));
    asm volatile("global_load_dwordx4 %0, %1, off offset:48 sc0 sc1" : "=v"(sreg[3]) : "v"(pb));
  }
}
__device__ inline void stage_write(unsigned short* buf, int tid, const u32x4 sreg[4]) {
  int row = tid >> 4;
  char* b = (char*)buf + row * 1024;
  int off = (tid & 15) * 64;
  #pragma unroll
  for (int i = 0; i < 4; ++i)
    *(u32x4*)(b + ((off + i * 16) ^ ((row & 7) << 4))) = sreg[i];
}

// one-time global generation barrier (agent scope)
__device__ inline void global_barrier_once(unsigned* bar) {
  __syncthreads();
  if (threadIdx.x == 0) {
    unsigned a = __hip_atomic_fetch_add(bar, 1u, __ATOMIC_ACQ_REL, __HIP_MEMORY_SCOPE_AGENT);
    if (a == NWGS - 1) {
      __hip_atomic_store(bar + 16, 1u, __ATOMIC_RELEASE, __HIP_MEMORY_SCOPE_AGENT);
    } else {
      #pragma unroll 1
      while (__hip_atomic_load(bar + 16, __ATOMIC_ACQUIRE, __HIP_MEMORY_SCOPE_AGENT) == 0u)
        __builtin_amdgcn_s_sleep(2);
    }
  }
  __syncthreads();
}

// =================== pack kernel ===================
__global__ void pack_kernel(const float* __restrict__ w_ih, const float* __restrict__ w_hh,
                            const float* __restrict__ w_out, const float* __restrict__ b_out,
                            const float* __restrict__ w_mode, const float* __restrict__ b_mode,
                            unsigned char* __restrict__ ws) {
  unsigned idx = blockIdx.x * 256 + threadIdx.x;
  if (idx < 2097152u) {          // weff [0,1M) / wplain [1M,2M)
    unsigned j = idx & 1048575u;
    bool eff = idx < 1048576u;
    unsigned e = j & 7u, lane = (j >> 3) & 63u, kb = (j >> 9) & 15u, T = j >> 13;
    unsigned i = lane & 15u;
    unsigned hcol = T * 4u + (i >> 2), gate = i & 3u;
    unsigned n = gate * 512u + hcol;
    unsigned k = kb * 32u + (lane >> 4) * 8u + e;
    float v = w_hh[(size_t)n * 512u + k];
    if (eff) v += w_ih[(size_t)n * 514u] * w_out[k] + w_ih[(size_t)n * 514u + 1u] * w_out[512u + k];
    ((unsigned short*)(ws + (eff ? WEFF_OFF : WPLAIN_OFF)))[j] = (unsigned short)f2bf(v);
  } else if (idx < 3145728u) {   // wihs (old layout, for prep)
    unsigned j = idx - 2097152u;
    unsigned e = j & 7u, lane = (j >> 3) & 63u, kb = (j >> 9) & 15u, nb = j >> 13;
    unsigned n = nb * 16u + (lane & 15u), k = kb * 32u + (lane >> 4) * 8u + e;
    ((unsigned short*)(ws + WIHS_OFF))[j] = (unsigned short)f2bf(w_ih[(size_t)n * 514u + 2u + k]);
  } else if (idx < 3162112u) {   // wsm: [w_out;w_mode;0]
    unsigned j = idx - 3145728u;
    unsigned e = j & 7u, lane = (j >> 3) & 63u, kb = (j >> 9) & 15u, nb = j >> 13;
    unsigned o = nb * 16u + (lane & 15u), k = kb * 32u + (lane >> 4) * 8u + e;
    float v = 0.0f;
    if (o < 12u) v = w_out[o * 512u + k];
    else if (o < 18u) v = w_mode[(o - 12u) * 512u + k];
    ((unsigned short*)(ws + WSM_OFF))[j] = (unsigned short)f2bf(v);
  } else if (idx < 3162144u) {   // bsm
    unsigned o = idx - 3162112u;
    float v = 0.0f;
    if (o < 12u) v = b_out[o];
    else if (o < 18u) v = b_mode[o - 12u];
    ((float*)(ws + BSM_OFF))[o] = v;
  } else if (idx < 3164192u) {   // bias_x (tile-row order)
    unsigned m = idx - 3162144u;
    unsigned T = m >> 4, i = m & 15u;
    unsigned hcol = T * 4u + (i >> 2), gate = i & 3u;
    unsigned n = gate * 512u + hcol;
    ((float*)(ws + BX1_OFF))[m] = w_ih[(size_t)n * 514u] * b_out[0] + w_ih[(size_t)n * 514u + 1u] * b_out[1];
  } else if (idx < 3166240u) {
    ((float*)(ws + BX0_OFF))[idx - 3164192u] = 0.0f;
  } else if (idx < 3166272u) {   // barrier state zeroed every launch
    ((unsigned*)(ws + BAR_OFF))[idx - 3166240u] = 0u;
  } else if (idx < 3166528u) {
    ((unsigned*)(ws + XCDT_OFF))[idx - 3166272u] = 0xFFFFFFFFu;
  } else if (idx < 3168576u) {   // flags zeroed every launch (replay-safe)
    ((unsigned*)(ws + FLAGS_OFF))[idx - 3166528u] = 0u;
  }
}

// =================== prep kernel: S, h0->bf16, c0 repack ===================
__global__ __launch_bounds__(512, 2) void prep_kernel(
    const float* __restrict__ social, const float* __restrict__ hidden,
    const float* __restrict__ cell, const float* __restrict__ b_ih,
    const float* __restrict__ b_hh, unsigned char* __restrict__ ws) {
  const int tid = threadIdx.x;
  const int wid = tid >> 6;
  const int lane = tid & 63;
  const int q = lane >> 4;
  const int r = lane & 15;
  const int wg = blockIdx.x;
  const int gb0 = wg * 32;

  const s16x8* wihs_w = (const s16x8*)(ws + WIHS_OFF) + (size_t)wid * 4096 + lane;
  unsigned short* spack = (unsigned short*)(ws + SPACK_OFF);
  unsigned short* hb0 = (unsigned short*)(ws + HB0_OFF);
  float* cpackp = (float*)(ws + CPACK_OFF);

  __shared__ unsigned short h_lds[32 * H];

  s16x8 wbuf[4][4];
  #pragma unroll
  for (int d = 0; d < 4; ++d)
    #pragma unroll
    for (int g = 0; g < 4; ++g)
      wbuf[d][g] = wihs_w[g * 32768 + d * 64];

  #pragma unroll
  for (int i = 0; i < 8; ++i) {
    int rr = i * 4 + (tid >> 7);
    int kk = (tid & 127) * 4;
    f32x4 v = *(const f32x4*)(social + (size_t)(gb0 + rr) * H + kk);
    u32x2 p;
    p[0] = f2bf(v[0]) | (f2bf(v[1]) << 16);
    p[1] = f2bf(v[2]) | (f2bf(v[3]) << 16);
    *(u32x2*)((char*)h_lds + haddr(rr, kk)) = p;
  }
  __syncthreads();

  #pragma unroll
  for (int jb = 0; jb < 4; ++jb) {
    f32x4 acc[4][2];
    #pragma unroll
    for (int g = 0; g < 4; ++g) {
      int n0 = g * 512 + wid * 64 + jb * 16 + q * 4;
      f32x4 bi = *(const f32x4*)(b_ih + n0);
      f32x4 bh = *(const f32x4*)(b_hh + n0);
      f32x4 bias = bi + bh;
      acc[g][0] = bias; acc[g][1] = bias;
    }
    #pragma unroll
    for (int kb = 0; kb < 16; ++kb) {
      const int F = jb * 16 + kb;
      const int slot = F & 3;
      s16x8 bfrag[2];
      #pragma unroll
      for (int bb = 0; bb < 2; ++bb)
        bfrag[bb] = *(const s16x8*)((char*)h_lds + haddr(bb * 16 + r, kb * 32 + q * 8));
      s16x8 af[4];
      #pragma unroll
      for (int g = 0; g < 4; ++g) af[g] = wbuf[slot][g];
      {
        const int Fn = (F + 4) & 63;
        const int jn = Fn >> 4, kn = Fn & 15;
        #pragma unroll
        for (int g = 0; g < 4; ++g)
          wbuf[slot][g] = wihs_w[g * 32768 + jn * 1024 + kn * 64];
      }
      #pragma unroll
      for (int g = 0; g < 4; ++g) {
        acc[g][0] = mfma16(af[g], bfrag[0], acc[g][0]);
        acc[g][1] = mfma16(af[g], bfrag[1], acc[g][1]);
      }
    }
    #pragma unroll
    for (int bb = 0; bb < 2; ++bb) {
      unsigned wrd[8];
      #pragma unroll
      for (int j = 0; j < 8; ++j) {
        int e = j >> 1, gp = (j & 1) * 2;
        wrd[j] = f2bf(acc[gp][bb][e]) | (f2bf(acc[gp + 1][bb][e]) << 16);
      }
      int T = wid * 16 + jb * 4 + q;
      int b = gb0 + bb * 16 + r;
      char* dst = (char*)spack + ((size_t)T * 8192 + b) * 32;
      u32x4 w0; w0[0] = wrd[0]; w0[1] = wrd[1]; w0[2] = wrd[2]; w0[3] = wrd[3];
      u32x4 w1; w1[0] = wrd[4]; w1[1] = wrd[5]; w1[2] = wrd[6]; w1[3] = wrd[7];
      *(u32x4*)dst = w0;
      *(u32x4*)(dst + 16) = w1;
    }
  }

  {
    const float* hsrc = hidden + (size_t)gb0 * H;
    unsigned short* hdst = hb0 + (size_t)gb0 * H;
    int base = tid * 32;
    #pragma unroll
    for (int v8 = 0; v8 < 4; ++v8) {
      f32x4 x0 = *(const f32x4*)(hsrc + base + v8 * 8);
      f32x4 x1 = *(const f32x4*)(hsrc + base + v8 * 8 + 4);
      u32x4 pk;
      pk[0] = f2bf(x0[0]) | (f2bf(x0[1]) << 16);
      pk[1] = f2bf(x0[2]) | (f2bf(x0[3]) << 16);
      pk[2] = f2bf(x1[0]) | (f2bf(x1[1]) << 16);
      pk[3] = f2bf(x1[2]) | (f2bf(x1[3]) << 16);
      *(u32x4*)(hdst + base + v8 * 8) = pk;
    }
  }

  for (int j = 0; j < 32; ++j) {
    int flat = tid * 32 + j;
    int b = gb0 + (flat >> 9);
    int hcol = flat & 511;
    float v = cell[(size_t)b * 512 + hcol];
    int jg2 = hcol >> 6, w2 = (hcol >> 3) & 7, Tl = (hcol >> 2) & 1, q2 = hcol & 3;
    int bg2 = b >> 8, ib2 = (b >> 4) & 15, r2 = b & 15;
    int wg2 = jg2 * 32 + bg2;
    cpackp[(((size_t)(wg2 * 8 + w2) * 16 + ib2) * 2 + Tl) * 64 + q2 * 16 + r2] = v;
  }
}

// =================== persistent kernel: all 60 steps ===================
__global__ __attribute__((amdgpu_flat_work_group_size(512, 512), amdgpu_waves_per_eu(2, 2)))
void coop_kernel(
    const s16x8* __restrict__ weff, const s16x8* __restrict__ wplain,
    const float* __restrict__ bx, const unsigned short* __restrict__ spack,
    const s16x8* __restrict__ wsm, const float* __restrict__ bsm,
    unsigned short* __restrict__ hb0, unsigned short* __restrict__ hb1,
    float* __restrict__ cpack, float* __restrict__ out,
    unsigned* __restrict__ flags, unsigned* __restrict__ xcdt,
    unsigned* __restrict__ bar) {
  const int tid = threadIdx.x;
  const int wid = tid >> 6;
  const int lane = tid & 63;
  const int q = lane >> 4;
  const int r = lane & 15;
  const int wg = blockIdx.x;
  const int jg = wg >> 5;        // 0..7 hidden-col group (64 cols)
  const int bg = wg & 31;        // 0..31 batch group (256 rows); partners wg=bg+32j
  const int b0 = bg * 256;
  const size_t MODE_BASE = (size_t)BATCHN * 720;

  __shared__ s16x8 wsm_lds[2048];                 // 32 KB
  __shared__ unsigned short hinA[32 * 512];       // 32 KB swizzled
  __shared__ unsigned short hinB[32 * 512];       // 32 KB
  __shared__ unsigned short hout_lds[256 * 64];   // 32 KB swizzled
  __shared__ float mode_lds[8][16][8];            // 4 KB
  __shared__ int fastf_lds;

  // ---- publish XCD id (fast path iff all 8 bg-partners co-located) ----
  unsigned xcd;
  asm volatile("s_getreg_b32 %0, hwreg(20, 0, 32)" : "=s"(xcd));
  if (tid == 0)
    __hip_atomic_store(&xcdt[wg], xcd & 0xFu, __ATOMIC_RELEASE, __HIP_MEMORY_SCOPE_AGENT);

  // ---- A fragments: asm loads directly into array elements, pinned ----
  s16x8 A0[16], A1[16];
  {
    const s16x8* ab = wplain + (size_t)((jg * 16 + wid * 2) * 16) * 64 + lane;
    #pragma unroll
    for (int kb = 0; kb < 16; ++kb) {
      asm volatile("global_load_dwordx4 %0, %1, off" : "=v"(A0[kb]) : "v"(ab + kb * 64));
      asm volatile("global_load_dwordx4 %0, %1, off" : "=v"(A1[kb]) : "v"(ab + kb * 64 + 1024));
    }
  }
  vm_drain();

  // ---- c stays in GLOBAL (WG-private, own-L2 round trip) ----
  float* cb = cpack + (size_t)(wg * 8 + wid) * 2048 + lane;

  #pragma unroll
  for (int i = 0; i < 4; ++i) wsm_lds[i * 512 + tid] = wsm[i * 512 + tid];

  const char* sp0 = (const char*)spack + ((size_t)(jg * 16 + wid * 2 + 0) * 8192) * 32 + q * 8;
  const char* sp1 = (const char*)spack + ((size_t)(jg * 16 + wid * 2 + 1) * 8192) * 32 + q * 8;

  // ---- one-time global barrier, then partner-XCD equality check ----
  global_barrier_once(bar);
  if (tid == 0) {
    unsigned mine = xcd & 0xFu;
    bool same = true;
    for (int j = 0; j < 8; ++j) {
      unsigned v = __hip_atomic_load(&xcdt[bg + 32 * j], __ATOMIC_ACQUIRE, __HIP_MEMORY_SCOPE_AGENT);
      same = same && (v == mine);
    }
    fastf_lds = same ? 1 : 0;
  }
  __syncthreads();
  const bool fast = (fastf_lds != 0);

  #pragma unroll 1
  for (int s = 0; s < STEPS; ++s) {
    const unsigned short* h_in = (s & 1) ? hb1 : hb0;
    unsigned short* h_out = (s & 1) ? hb0 : hb1;
    f32x4 bxv0 = *(const f32x4*)(bx + (jg * 16 + wid * 2 + 0) * 16 + q * 4);
    f32x4 bxv1 = *(const f32x4*)(bx + (jg * 16 + wid * 2 + 1) * 16 + q * 4);
    if (s == 0) {
      f32x4 z = {0.f, 0.f, 0.f, 0.f};
      bxv0 = z; bxv1 = z;
    }

    u32x4 sreg[4];
    stage_issue(h_in, b0, 0, tid, fast, sreg);
    vm_drain();
    stage_write(hinA, tid, sreg);
    stage_issue(h_in, b0, 1, tid, fast, sreg);
    u32x2 sv0 = *(const u32x2*)(sp0 + (size_t)(b0 + r) * 32);
    u32x2 sv1 = *(const u32x2*)(sp1 + (size_t)(b0 + r) * 32);
    float cvn0 = cb[0], cvn1 = cb[64];   // prefetch c for bt=0
    __syncthreads();

    #pragma unroll
    for (int rr = 0; rr < 8; ++rr) {
      if (rr < 7) {
        unsigned short* wb = ((rr + 1) & 1) ? hinB : hinA;
        vm_drain();
        stage_write(wb, tid, sreg);
        if (rr < 6) stage_issue(h_in, b0, rr + 2, tid, fast, sreg);
      }
      const unsigned short* hbuf = (rr & 1) ? hinB : hinA;
      const bool dop = (wid == rr) && (s > 0);
      #pragma unroll
      for (int ib2 = 0; ib2 < 2; ++ib2) {
        const int bt = rr * 2 + ib2;
        const int b = b0 + bt * 16 + r;
        u32x2 cs0 = sv0, cs1 = sv1;
        float cva0 = cvn0, cva1 = cvn1;
        if (bt < 15) {
          sv0 = *(const u32x2*)(sp0 + (size_t)(b + 16) * 32);
          sv1 = *(const u32x2*)(sp1 + (size_t)(b + 16) * 32);
          cvn0 = cb[(bt + 1) * 128];
          cvn1 = cb[(bt + 1) * 128 + 64];
        }
        f32x4 acc0, acc1;
        acc0[0] = bf2f(cs0[0] & 0xffffu) + bxv0[0];
        acc0[1] = bf2f(cs0[0] >> 16)     + bxv0[1];
        acc0[2] = bf2f(cs0[1] & 0xffffu) + bxv0[2];
        acc0[3] = bf2f(cs0[1] >> 16)     + bxv0[3];
        acc1[0] = bf2f(cs1[0] & 0xffffu) + bxv1[0];
        acc1[1] = bf2f(cs1[0] >> 16)     + bxv1[1];
        acc1[2] = bf2f(cs1[1] & 0xffffu) + bxv1[2];
        acc1[3] = bf2f(cs1[1] >> 16)     + bxv1[3];
        #pragma unroll
        for (int kb = 0; kb < 16; ++kb) {
          s16x8 bfrag = *(const s16x8*)((const char*)hbuf + (ib2 * 16 + r) * 1024 +
                          ((kb * 64 + q * 16) ^ ((r & 7) << 4)));
          acc0 = mfma16(A0[kb], bfrag, acc0);
          acc1 = mfma16(A1[kb], bfrag, acc1);
        }
        #pragma unroll
        for (int Tl = 0; Tl < 2; ++Tl) {
          f32x4 ac = Tl ? acc1 : acc0;
          float cold = Tl ? cva1 : cva0;
          float iv = sigm(ac[0]), fv = sigm(ac[1]), gv = tanh_(ac[2]), ov = sigm(ac[3]);
          float cn = fv * cold + iv * gv;
          cb[bt * 128 + Tl * 64] = cn;   // plain store, own-L2
          float hn = ov * tanh_(cn);
          int col = wid * 8 + Tl * 4 + q;
          int row = bt * 16 + r;
          *(unsigned short*)((char*)hout_lds + row * 128 + ((col * 2) ^ ((r & 7) << 4))) =
              (unsigned short)f2bf(hn);
        }
        if (dop) {  // projection of h(s) -> pred/modes at t = s-1
          const int tprev = s - 1;
          f32x4 p0 = *(const f32x4*)(bsm + q * 4);
          f32x4 p1 = *(const f32x4*)(bsm + 16 + q * 4);
          #pragma unroll
          for (int kb = 0; kb < 16; ++kb) {
            s16x8 bfrag = *(const s16x8*)((const char*)hbuf + (ib2 * 16 + r) * 1024 +
                            ((kb * 64 + q * 16) ^ ((r & 7) << 4)));
            p0 = mfma16(wsm_lds[kb * 64 + lane], bfrag, p0);
            p1 = mfma16(wsm_lds[(16 + kb) * 64 + lane], bfrag, p1);
          }
          if (q < 3) *(f32x4*)(out + ((size_t)b * 60 + tprev) * 12 + q * 4) = p0;
          if (q == 3) *(f32x4*)(&mode_lds[wid][r][0]) = p0;
          if (q == 0) { mode_lds[wid][r][4] = p1[0]; mode_lds[wid][r][5] = p1[1]; }
          if (q == 1) {
            float v0 = mode_lds[wid][r][0], v1 = mode_lds[wid][r][1], v2 = mode_lds[wid][r][2];
            float v3 = mode_lds[wid][r][3], v4 = mode_lds[wid][r][4], v5 = mode_lds[wid][r][5];
            float mx = fmaxf(fmaxf(fmaxf(v0, v1), fmaxf(v2, v3)), fmaxf(v4, v5));
            float e0 = __builtin_amdgcn_exp2f(1.442695041f * (v0 - mx));
            float e1 = __builtin_amdgcn_exp2f(1.442695041f * (v1 - mx));
            float e2 = __builtin_amdgcn_exp2f(1.442695041f * (v2 - mx));
            float e3 = __builtin_amdgcn_exp2f(1.442695041f * (v3 - mx));
            float e4 = __builtin_amdgcn_exp2f(1.442695041f * (v4 - mx));
            float e5 = __builtin_amdgcn_exp2f(1.442695041f * (v5 - mx));
            float su = e0 + e1 + e2 + e3 + e4 + e5;
            float inv = __builtin_amdgcn_rcpf(su);
            float* mo = out + MODE_BASE + (size_t)b * 360 + tprev * 6;
            mo[0] = e0 * inv; mo[1] = e1 * inv; mo[2] = e2 * inv;
            mo[3] = e3 * inv; mo[4] = e4 * inv; mo[5] = e5 * inv;
          }
        }
      }
      __syncthreads();
    }
    // flush h_out: fast = plain stores (shared XCD L2), slow = sc1; drain
    {
      int row = tid >> 1;
      int off0 = (tid & 1) * 64;
      u32x4 v0 = *(const u32x4*)((const char*)hout_lds + row * 128 + ((off0 +  0) ^ ((row & 7) << 4)));
      u32x4 v1 = *(const u32x4*)((const char*)hout_lds + row * 128 + ((off0 + 16) ^ ((row & 7) << 4)));
      u32x4 v2 = *(const u32x4*)((const char*)hout_lds + row * 128 + ((off0 + 32) ^ ((row & 7) << 4)));
      u32x4 v3 = *(const u32x4*)((const char*)hout_lds + row * 128 + ((off0 + 48) ^ ((row & 7) << 4)));
      char* dst = (char*)h_out + (size_t)(b0 + row) * 1024 + jg * 128 + off0;
      if (fast) {
        asm volatile(
            "global_store_dwordx4 %0, %1, off\n\t"
            "global_store_dwordx4 %0, %2, off offset:16\n\t"
            "global_store_dwordx4 %0, %3, off offset:32\n\t"
            "global_store_dwordx4 %0, %4, off offset:48"
            :: "v"(dst), "v"(v0), "v"(v1), "v"(v2), "v"(v3) : "memory");
      } else {
        asm volatile(
            "global_store_dwordx4 %0, %1, off sc0 sc1\n\t"
            "global_store_dwordx4 %0, %2, off offset:16 sc0 sc1\n\t"
            "global_store_dwordx4 %0, %3, off offset:32 sc0 sc1\n\t"
            "global_store_dwordx4 %0, %4, off offset:48 sc0 sc1"
            :: "v"(dst), "v"(v0), "v"(v1), "v"(v2), "v"(v3) : "memory");
      }
      asm volatile("s_waitcnt vmcnt(0)" ::: "memory");
    }
    // per-bg 8-WG sync (32 independent groups, no global convoy)
    if (s < STEPS - 1) {
      __syncthreads();
      if (tid == 0) {
        unsigned* f = &flags[bg * 64 + s];
        __hip_atomic_fetch_add(f, 1u, __ATOMIC_RELAXED, __HIP_MEMORY_SCOPE_AGENT);
        unsigned v;
        #pragma unroll 1
        do {
          v = __hip_atomic_load(f, __ATOMIC_RELAXED, __HIP_MEMORY_SCOPE_AGENT);
          if (v < 8u) __builtin_amdgcn_s_sleep(1);
        } while (v < 8u);
      }
      __syncthreads();
    }
    if (s == 0) {  // switch to folded weights (direct asm reload)
      const s16x8* ab = weff + (size_t)((jg * 16 + wid * 2) * 16) * 64 + lane;
      #pragma unroll
      for (int kb = 0; kb < 16; ++kb) {
        asm volatile("global_load_dwordx4 %0, %1, off" : "=v"(A0[kb]) : "v"(ab + kb * 64));
        asm volatile("global_load_dwordx4 %0, %1, off" : "=v"(A1[kb]) : "v"(ab + kb * 64 + 1024));
      }
      vm_drain();
    }
  }
}

// =================== final projection (t=59), sc1 h loads ===================
__global__ __launch_bounds__(256) void projf_kernel(
    const unsigned short* __restrict__ h_in, const s16x8* __restrict__ wsm,
    const float* __restrict__ bsm, float* __restrict__ out) {
  const int tid = threadIdx.x;
  const int wid = tid >> 6;
  const int lane = tid & 63;
  const int q = lane >> 4;
  const int r = lane & 15;
  const int wg = blockIdx.x;
  const int b0 = wg * 32;
  const int bt = wid & 1, T = wid >> 1;
  const size_t MODE_BASE = (size_t)BATCHN * 720;
  __shared__ float mbuf[32][8];

  // device-scope loads (kernel-boundary writeback makes both modes visible)
  u32x4 hf[16];
  const char* hbase = (const char*)h_in + (size_t)(b0 + bt * 16 + r) * 1024 + q * 16;
  #pragma unroll
  for (int g = 0; g < 16; ++g) {
    asm volatile("global_load_dwordx4 %0, %1, off sc0 sc1"
                 : "=v"(hf[g]) : "v"(hbase + g * 64));
  }
  asm volatile("s_waitcnt vmcnt(0)" ::: "memory");
  __builtin_amdgcn_sched_barrier(0);

  f32x4 pacc = *(const f32x4*)(bsm + T * 16 + q * 4);
  #pragma unroll
  for (int kb = 0; kb < 16; ++kb) {
    s16x8 bfrag = __builtin_bit_cast(s16x8, hf[kb]);
    s16x8 af = wsm[(T * 16 + kb) * 64 + lane];
    pacc = mfma16(af, bfrag, pacc);
  }
  int b = b0 + bt * 16 + r;
  if (T == 0) {
    if (q < 3) *(f32x4*)(out + ((size_t)b * 60 + 59) * 12 + q * 4) = pacc;
    if (q == 3) *(f32x4*)(&mbuf[bt * 16 + r][0]) = pacc;
  } else {
    if (q == 0) { mbuf[bt * 16 + r][4] = pacc[0]; mbuf[bt * 16 + r][5] = pacc[1]; }
  }
  __syncthreads();
  if (tid < 32) {
    float v0 = mbuf[tid][0], v1 = mbuf[tid][1], v2 = mbuf[tid][2];
    float v3 = mbuf[tid][3], v4 = mbuf[tid][4], v5 = mbuf[tid][5];
    float mx = fmaxf(fmaxf(fmaxf(v0, v1), fmaxf(v2, v3)), fmaxf(v4, v5));
    float e0 = __builtin_amdgcn_exp2f(1.442695041f * (v0 - mx));
    float e1 = __builtin_amdgcn_exp2f(1.442695041f * (v1 - mx));
    float e2 = __builtin_amdgcn_exp2f(1.442695041f * (v2 - mx));
    float e3 = __builtin_amdgcn_exp2f(1.442695041f * (v3 - mx));
    float e4 = __builtin_amdgcn_exp2f(1.442695041f * (v4 - mx));
    float e5 = __builtin_amdgcn_exp2f(1.442695041f * (v5 - mx));
    float s = e0 + e1 + e2 + e3 + e4 + e5;
    float inv = __builtin_amdgcn_rcpf(s);
    float* mo = out + MODE_BASE + (size_t)(b0 + tid) * 360 + 59 * 6;
    mo[0] = e0 * inv; mo[1] = e1 * inv; mo[2] = e2 * inv;
    mo[3] = e3 * inv; mo[4] = e4 * inv; mo[5] = e5 * inv;
  }
}

extern "C" void kernel_launch(void* const* d_in, const int* in_sizes, int n_in,
                              void* d_out, int out_size, void* d_ws, size_t ws_size,
                              hipStream_t stream) {
  const float* social = (const float*)d_in[0];
  const float* hidden = (const float*)d_in[1];
  const float* cell   = (const float*)d_in[2];
  const float* w_ih   = (const float*)d_in[3];
  const float* w_hh   = (const float*)d_in[4];
  const float* b_ih   = (const float*)d_in[5];
  const float* b_hh   = (const float*)d_in[6];
  const float* w_out  = (const float*)d_in[7];
  const float* b_out  = (const float*)d_in[8];
  const float* w_mode = (const float*)d_in[9];
  const float* b_mode = (const float*)d_in[10];
  unsigned char* ws = (unsigned char*)d_ws;
  float* out = (float*)d_out;

  hipLaunchKernelGGL(pack_kernel, dim3((3168576u + 255u) / 256u), dim3(256), 0, stream,
                     w_ih, w_hh, w_out, b_out, w_mode, b_mode, ws);
  hipLaunchKernelGGL(prep_kernel, dim3(256), dim3(512), 0, stream,
                     social, hidden, cell, b_ih, b_hh, ws);

  const s16x8* weff   = (const s16x8*)(ws + WEFF_OFF);
  const s16x8* wplain = (const s16x8*)(ws + WPLAIN_OFF);
  const s16x8* wsm    = (const s16x8*)(ws + WSM_OFF);
  const float* bsm    = (const float*)(ws + BSM_OFF);
  const float* bx1    = (const float*)(ws + BX1_OFF);
  const unsigned short* spack = (const unsigned short*)(ws + SPACK_OFF);
  unsigned short* hb0p = (unsigned short*)(ws + HB0_OFF);
  unsigned short* hb1p = (unsigned short*)(ws + HB1_OFF);
  float* cpackc = (float*)(ws + CPACK_OFF);
  unsigned* flagsp = (unsigned*)(ws + FLAGS_OFF);
  unsigned* xcdtp = (unsigned*)(ws + XCDT_OFF);
  unsigned* barp = (unsigned*)(ws + BAR_OFF);

  void* args[] = {(void*)&weff, (void*)&wplain, (void*)&bx1, (void*)&spack,
                  (void*)&wsm, (void*)&bsm, (void*)&hb0p, (void*)&hb1p,
                  (void*)&cpackc, (void*)&out, (void*)&flagsp, (void*)&xcdtp,
                  (void*)&barp};
  hipLaunchCooperativeKernel((const void*)coop_kernel, dim3(NWGS), dim3(512),
                             args, 0, stream);

  hipLaunchKernelGGL(projf_kernel, dim3(256), dim3(256), 0, stream,
                     hb0p, wsm, bsm, out);
}